// Round 11
// baseline (555.728 us; speedup 1.0000x reference)
//
#include <hip/hip_runtime.h>
#include <cstdint>
#include <cstddef>

#define NV 50000
#define ED 128
#define SS 50
#define NB 128
#define NM 200
#define BMD (NB*NM*ED)   // 3,276,800 floats per table
#define NCH 32
#define CHD 1563         // ceil(50000/32)

typedef _Float16 f16x8 __attribute__((ext_vector_type(8)));
typedef _Float16 f16x4 __attribute__((ext_vector_type(4)));
typedef _Float16 f16x2 __attribute__((ext_vector_type(2)));
typedef float    f32x4 __attribute__((ext_vector_type(4)));

// ---------------------------------------------------------------------------
// LEDGER: fp16 score path REFUTED (r1/r3). LLC warm REFUTED (r4). 2-wide row
// unroll REFUTED (r5). 8bm/block REFUTED (r6). table-split REFUTED (r7: FETCH
// floor confirmed at 377MB but 1-load/iter kills MLP). 32bm/512thr REFUTED
// (r10: 8-wave barrier imbalance). Block geometry axis mapped: 16bm/4-wave
// optimal. Rest-block (hops+out_mm+gaps) = 154-158us across SIX structural
// variants -> traffic/overhead-bound, frozen this round.
// THIS ROUND: d-split story — halve per-XCD row bytes via blockIdx%8 XCD
// affinity (mapping validated by r7's FETCH), keeping 4-deep load MLP.
// ---------------------------------------------------------------------------
__global__ __launch_bounds__(256) void cvt_c3_k(
    const float* __restrict__ src, _Float16* __restrict__ dst) {
  const int i = blockIdx.x * 256 + threadIdx.x;   // f16x8 group, < 800000
  const float4* s4 = (const float4*)src;
  float4 f0 = s4[2 * (size_t)i];
  float4 f1 = s4[2 * (size_t)i + 1];
  f16x8 h;
  h[0] = (_Float16)f0.x; h[1] = (_Float16)f0.y;
  h[2] = (_Float16)f0.z; h[3] = (_Float16)f0.w;
  h[4] = (_Float16)f1.x; h[5] = (_Float16)f1.y;
  h[6] = (_Float16)f1.z; h[7] = (_Float16)f1.w;
  *(f16x8*)(dst + (size_t)8 * i) = h;
}

// ---------------------------------------------------------------------------
// Kernel A: vocab-chunked gather-reduce, D-SPLIT across XCD halves.
// blockIdx = j*8 + s8. dhalf = s8>>2 (XCDs 0-3 take d[0,64), XCDs 4-7 take
// d[64,128) under round-robin dispatch); bmset = j*4 + (s8&3) in [0,1600).
// Each block: r2's exact 16bm/4-wave/4-table inner loop, but each lane owns
// ONE d (4B fp32 loads, 2B fp16): per-XCD compulsory row bytes halve
// (512B->256B per fp32 table) while load MLP stays 4-deep. Accumulation
// order per (bm,d) unchanged -> bit-identical Mt.
// ---------------------------------------------------------------------------
__global__ __launch_bounds__(256) void story_embed_k(
    const int* __restrict__ story, const float* __restrict__ C,
    const _Float16* __restrict__ C3h, float* __restrict__ Mt) {
  const int s8    = blockIdx.x & 7;
  const int dhalf = s8 >> 2;                         // 0 or 1
  const int bmset = (blockIdx.x >> 3) * 4 + (s8 & 3); // 0..1599
  const int wave = threadIdx.x >> 6;
  const int lane = threadIdx.x & 63;
  const int bm0 = bmset * 16;
  const int d = dhalf * 64 + lane;
  const int sl = (lane < SS) ? lane : (SS - 1);

  int idxg[4], cidg[4];
#pragma unroll
  for (int gg = 0; gg < 4; ++gg) {
    const int bm = bm0 + wave + 4 * gg;
    idxg[gg] = story[(size_t)bm * SS + sl];
    cidg[gg] = (lane < SS) ? (idxg[gg] / CHD) : -1;
  }
  const float ad = ((float)(d + 1) - 64.5f) * 6.25e-4f;
  float acc[4][4];
#pragma unroll
  for (int gg = 0; gg < 4; ++gg)
#pragma unroll
    for (int k = 0; k < 4; ++k) acc[gg][k] = 0.f;

  for (int c = 0; c < NCH; ++c) {
#pragma unroll
    for (int gg = 0; gg < 4; ++gg) {
      unsigned long long mask = __ballot(cidg[gg] == c);
      while (mask) {
        const int s = __builtin_ctzll(mask);
        mask &= mask - 1;
        const int row = __shfl(idxg[gg], s);
        float e;
        if (s == SS - 1) e = 1.0f;
        else {
          float js = (float)(s + 1) - 25.5f;
          e = fmaf(ad, js, 1.0f);
        }
        const float* base = C + (size_t)row * ED + d;
#pragma unroll
        for (int k = 0; k < 3; ++k) {
          float cv = base[(size_t)k * NV * ED];
          acc[gg][k] = fmaf(e, cv, acc[gg][k]);
        }
        float cv3 = (float)C3h[(size_t)row * ED + d];
        acc[gg][3] = fmaf(e, cv3, acc[gg][3]);
      }
    }
    __syncthreads();
  }

#pragma unroll
  for (int gg = 0; gg < 4; ++gg) {
    const int bm = bm0 + wave + 4 * gg;
#pragma unroll
    for (int k = 0; k < 4; ++k)
      Mt[(size_t)k * BMD + (size_t)bm * ED + d] = acc[gg][k];
  }
}

// ---------------------------------------------------------------------------
// Kernel B: hop loop — r10-passing version, byte-identical (frozen control).
// ---------------------------------------------------------------------------
__global__ __launch_bounds__(512, 1) void hops_k(
    const int* __restrict__ query, const float* __restrict__ C,
    const float* __restrict__ Tw, const float* __restrict__ Tb,
    const float* __restrict__ Mt, float* __restrict__ U) {
  const int b = blockIdx.x;
  const int tid = threadIdx.x;                   // 0..511
  const int d = tid & 127;
  const int p = tid >> 7;                        // 0..3
  const int wave = tid >> 6, lane = tid & 63;
  __shared__ float tile[NM * ED];                // 102,400 B
  __shared__ float u[ED];
  __shared__ float part[512];
  __shared__ float part2[512];
  __shared__ float sc[NM];
  __shared__ float sc2[NM];

  {
    const float4* s4 = (const float4*)(Mt + (size_t)b * NM * ED);
    float4* t4 = (float4*)tile;
    float4 st[13];
#pragma unroll
    for (int j = 0; j < 13; ++j) {
      int i = tid + 512 * j;
      st[j] = (i < NM * ED / 4) ? s4[i] : make_float4(0.f, 0.f, 0.f, 0.f);
    }
#pragma unroll
    for (int j = 0; j < 13; ++j) {
      int i = tid + 512 * j;
      if (i < NM * ED / 4) t4[i] = st[j];
    }
  }

  {
    const float ad = ((float)(d + 1) - 64.5f) * 6.25e-4f;
    int rows[13];
#pragma unroll
    for (int j = 0; j < 13; ++j) {
      int s = p + 4 * j;
      rows[j] = query[b * SS + (s < SS ? s : 0)];
    }
    float cv[13];
#pragma unroll
    for (int j = 0; j < 13; ++j)
      cv[j] = C[(size_t)rows[j] * ED + d];
    float accv = 0.f;
#pragma unroll
    for (int j = 0; j < 13; ++j) {
      int s = p + 4 * j;
      float e;
      if (s >= SS) e = 0.f;
      else if (s == SS - 1) e = 1.0f;
      else e = fmaf(ad, (float)(s + 1) - 25.5f, 1.0f);
      accv = fmaf(e, cv[j], accv);
    }
    part[tid] = accv;
  }
  __syncthreads();
  if (tid < ED)
    u[tid] = part[tid] + part[tid + 128] + part[tid + 256] + part[tid + 384];
  __syncthreads();

  for (int hop = 0; hop < 3; ++hop) {
    const float* Tn = Mt + (size_t)(hop + 1) * BMD + (size_t)b * NM * ED;
    float pf[50];
#pragma unroll
    for (int j = 0; j < 50; ++j)
      pf[j] = Tn[(size_t)(p + 4 * j) * ED + d];

    {
      float u0v = u[2 * lane], u1v = u[2 * lane + 1];
      for (int m = wave; m < NM; m += 16) {
        const int m2 = m + 8;
        const bool has2 = (m2 < NM);
        float2 r0 = *(const float2*)&tile[m * ED + 2 * lane];
        float pa = r0.x * u0v + r0.y * u1v;
        float pb = 0.f;
        if (has2) {
          float2 r1 = *(const float2*)&tile[m2 * ED + 2 * lane];
          pb = r1.x * u0v + r1.y * u1v;
        }
#pragma unroll
        for (int off = 32; off; off >>= 1) {
          pa += __shfl_xor(pa, off);
          pb += __shfl_xor(pb, off);
        }
        if (lane == 0) {
          sc[m] = pa;
          if (has2) sc[m2] = pb;
        }
      }
    }
    __syncthreads();                               // B1: raw scores ready

    const bool has3 = (lane + 192 < NM);           // lane < 8
    float v0 = sc[lane];
    float v1 = sc[lane + 64];
    float v2 = sc[lane + 128];
    float v3 = has3 ? sc[lane + 192] : -1e30f;
    float mx = fmaxf(fmaxf(v0, v1), fmaxf(v2, v3));
#pragma unroll
    for (int off = 32; off; off >>= 1) mx = fmaxf(mx, __shfl_xor(mx, off));
    float e0 = __expf(v0 - mx), e1 = __expf(v1 - mx), e2 = __expf(v2 - mx);
    float e3 = has3 ? __expf(v3 - mx) : 0.f;
    float ts = e0 + e1 + e2 + e3;
#pragma unroll
    for (int off = 32; off; off >>= 1) ts += __shfl_xor(ts, off);
    const float inv = 1.0f / ts;
    if (wave == 0) {
      sc2[lane] = e0; sc2[lane + 64] = e1; sc2[lane + 128] = e2;
      if (has3) sc2[lane + 192] = e3;
    }
    __syncthreads();                               // B2: sc2 = exp values

    {
      float oacc = 0.f;
#pragma unroll
      for (int j = 0; j < 50; ++j)
        oacc = fmaf(sc2[p + 4 * j], pf[j], oacc);
      part[tid] = oacc;

      const float4* twr = (const float4*)(Tw + (size_t)d * ED + p * 32);
      float4 tw4[8];
#pragma unroll
      for (int j = 0; j < 8; ++j) tw4[j] = twr[j];
      float tacc = 0.f;
#pragma unroll
      for (int j = 0; j < 8; ++j) {
        tacc = fmaf(u[p * 32 + 4 * j + 0], tw4[j].x, tacc);
        tacc = fmaf(u[p * 32 + 4 * j + 1], tw4[j].y, tacc);
        tacc = fmaf(u[p * 32 + 4 * j + 2], tw4[j].z, tacc);
        tacc = fmaf(u[p * 32 + 4 * j + 3], tw4[j].w, tacc);
      }
      part2[tid] = tacc;

      if (hop < 2) {
#pragma unroll
        for (int j = 0; j < 50; ++j)
          tile[(p + 4 * j) * ED + d] = pf[j];
      }
    }
    __syncthreads();                               // B3: partials ready

    if (tid < ED) {
      float ov = (part[tid] + part[tid + 128] + part[tid + 256]
                  + part[tid + 384]) * inv;
      float dot = part2[tid] + part2[tid + 128] + part2[tid + 256]
                  + part2[tid + 384] + Tb[tid];
      float tk = 1.0f / (1.0f + __expf(-dot));
      u[tid] = (1.0f - tk) * u[tid] + ov * tk;
    }
    __syncthreads();                               // B4: u ready for next hop
  }
  if (tid < ED) U[(size_t)b * ED + tid] = u[tid];
}

// ---------------------------------------------------------------------------
// Kernel C: a_hat = U @ C3^T via f16 MFMA (512 thr, 128 v/block — frozen).
// ---------------------------------------------------------------------------
__global__ __launch_bounds__(512) void out_mm_mfma_k(
    const float* __restrict__ U, const _Float16* __restrict__ C3h,
    float* __restrict__ out) {
  __shared__ _Float16 Ub[ED * 136];   // 34,816 B
  const int tid = threadIdx.x;

  {
    const float4* u4 = (const float4*)U;
#pragma unroll
    for (int j = 0; j < 8; ++j) {
      int i = tid + 512 * j;          // float4 index
      float4 f = u4[i];
      int row = i >> 5;
      int col = (i & 31) * 4;
      f16x4 h;
      h[0] = (_Float16)f.x; h[1] = (_Float16)f.y;
      h[2] = (_Float16)f.z; h[3] = (_Float16)f.w;
      *(f16x4*)&Ub[row * 136 + col] = h;
    }
  }
  __syncthreads();

  const int wave = tid >> 6, lane = tid & 63;
  const int n = lane & 15, q = lane >> 4;
  const int v = blockIdx.x * 128 + wave * 16 + n;
  const bool vok = (v < NV);

  f32x4 acc[8];
#pragma unroll
  for (int mt = 0; mt < 8; ++mt) acc[mt] = (f32x4){0.f, 0.f, 0.f, 0.f};

#pragma unroll
  for (int kt = 0; kt < 4; ++kt) {
    f16x8 bfrag = {};
    if (vok) bfrag = *(const f16x8*)(C3h + (size_t)v * ED + kt * 32 + q * 8);
#pragma unroll
    for (int mt = 0; mt < 8; ++mt) {
      f16x8 afrag = *(const f16x8*)&Ub[(mt * 16 + n) * 136 + kt * 32 + q * 8];
      acc[mt] = __builtin_amdgcn_mfma_f32_16x16x32_f16(afrag, bfrag, acc[mt],
                                                       0, 0, 0);
    }
  }

  if (vok) {
#pragma unroll
    for (int mt = 0; mt < 8; ++mt)
#pragma unroll
      for (int i = 0; i < 4; ++i)
        out[(size_t)(mt * 16 + q * 4 + i) * NV + v] = acc[mt][i];
  }
}

// ---------------------------------------------------------------------------
extern "C" void kernel_launch(void* const* d_in, const int* in_sizes, int n_in,
                              void* d_out, int out_size, void* d_ws, size_t ws_size,
                              hipStream_t stream) {
  const int*   story = (const int*)d_in[0];   // [128,200,50]
  const int*   query = (const int*)d_in[1];   // [128,50]
  const float* C     = (const float*)d_in[2]; // [4,50000,128]
  const float* Tw    = (const float*)d_in[3]; // [128,128]
  const float* Tb    = (const float*)d_in[4]; // [128]
  float* out = (float*)d_out;                 // [128,50000]

  float* wsf = (float*)d_ws;
  float*     Mt  = wsf;                                   // 4*BMD floats
  float*     U   = wsf + (size_t)4 * BMD;                 // 16384 floats
  _Float16*  C3h = (_Float16*)(wsf + (size_t)4 * BMD + NB * ED);

  hipLaunchKernelGGL(cvt_c3_k, dim3(NV * ED / 8 / 256), dim3(256), 0, stream,
                     C + (size_t)3 * NV * ED, C3h);
  // 2 d-halves x 1600 bm-sets; blockIdx%8 = (dhalf<<2)|sub for XCD affinity
  hipLaunchKernelGGL(story_embed_k, dim3(2 * NB * NM / 16), dim3(256), 0,
                     stream, story, C, C3h, Mt);
  hipLaunchKernelGGL(hops_k, dim3(NB), dim3(512), 0, stream,
                     query, C, Tw, Tb, Mt, U);
  hipLaunchKernelGGL(out_mm_mfma_k, dim3((NV + 127) / 128), dim3(512), 0, stream,
                     U, C3h, out);
}

// Round 12
// 355.710 us; speedup vs baseline: 1.5623x; 1.5623x over previous
//
#include <hip/hip_runtime.h>
#include <cstdint>
#include <cstddef>

#define NV 50000
#define ED 128
#define SS 50
#define NB 128
#define NM 200
#define BMD (NB*NM*ED)   // 3,276,800 floats per table
#define NCH 32
#define CHD 1563         // ceil(50000/32)

typedef _Float16 f16x8 __attribute__((ext_vector_type(8)));
typedef _Float16 f16x4 __attribute__((ext_vector_type(4)));
typedef _Float16 f16x2 __attribute__((ext_vector_type(2)));
typedef float    f32x4 __attribute__((ext_vector_type(4)));

// ---------------------------------------------------------------------------
// LEDGER: fp16 score path REFUTED (r1/r3). LLC warm REFUTED (r4). 2-wide row
// unroll REFUTED (r5). 8bm REFUTED (r6). table-split REFUTED (r7). 32bm/512t
// REFUTED (r10). d-split REFUTED (r11: FETCH 420MB but dur 2x — per-block
// serial gather time is width-invariant; block count is the cost).
// Geometry/precision/affinity axes fully mapped; r2 16bm/4-wave/4-table = optimum
// (193us = 86% of the 166us fetch floor). Rest-block 154-158us invariant
// across SIX hops/out_mm restructures.
// THIS ROUND (single variable): software-pipeline the pop loop — hoist next
// pop's ctz+shfl above current pop's loads. Load count/order/width/geometry
// unchanged -> FETCH must stay ~566MB (tripwire); only the serial chain
// shortens. Null => story at latency floor => ROOFLINE.
// ---------------------------------------------------------------------------
__global__ __launch_bounds__(256) void cvt_c3_k(
    const float* __restrict__ src, _Float16* __restrict__ dst) {
  const int i = blockIdx.x * 256 + threadIdx.x;   // f16x8 group, < 800000
  const float4* s4 = (const float4*)src;
  float4 f0 = s4[2 * (size_t)i];
  float4 f1 = s4[2 * (size_t)i + 1];
  f16x8 h;
  h[0] = (_Float16)f0.x; h[1] = (_Float16)f0.y;
  h[2] = (_Float16)f0.z; h[3] = (_Float16)f0.w;
  h[4] = (_Float16)f1.x; h[5] = (_Float16)f1.y;
  h[6] = (_Float16)f1.z; h[7] = (_Float16)f1.w;
  *(f16x8*)(dst + (size_t)8 * i) = h;
}

// ---------------------------------------------------------------------------
// Kernel A: r2-exact gather (16bm/4-wave/4-table), pop loop software-
// pipelined: shfl(i+1) overlaps loads(i). Accumulation order per (bm,d)
// unchanged -> bit-identical Mt.
// ---------------------------------------------------------------------------
__global__ __launch_bounds__(256) void story_embed_k(
    const int* __restrict__ story, const float* __restrict__ C,
    const _Float16* __restrict__ C3h, float* __restrict__ Mt) {
  const int wave = threadIdx.x >> 6;
  const int lane = threadIdx.x & 63;
  const int bm0 = blockIdx.x * 16;
  const int sl = (lane < SS) ? lane : (SS - 1);

  int idxg[4], cidg[4];
#pragma unroll
  for (int gg = 0; gg < 4; ++gg) {
    const int bm = bm0 + wave + 4 * gg;
    idxg[gg] = story[(size_t)bm * SS + sl];
    cidg[gg] = (lane < SS) ? (idxg[gg] / CHD) : -1;
  }
  const float a0 = ((float)(2*lane + 1) - 64.5f) * 6.25e-4f;
  const float a1 = ((float)(2*lane + 2) - 64.5f) * 6.25e-4f;
  float2 acc[4][4];
#pragma unroll
  for (int gg = 0; gg < 4; ++gg)
#pragma unroll
    for (int k = 0; k < 4; ++k) acc[gg][k] = make_float2(0.f, 0.f);

  for (int c = 0; c < NCH; ++c) {
#pragma unroll
    for (int gg = 0; gg < 4; ++gg) {
      unsigned long long mask = __ballot(cidg[gg] == c);
      if (!mask) continue;
      // ---- pipelined pop loop: next pop's shfl issues before current loads
      int s = __builtin_ctzll(mask);
      mask &= mask - 1;
      int row = __shfl(idxg[gg], s);
      while (true) {
        const bool more = (mask != 0);
        int s2 = 0;
        if (more) { s2 = __builtin_ctzll(mask); mask &= mask - 1; }
        const int row2 = __shfl(idxg[gg], s2);   // wave-uniform, issues early
        float e0, e1;
        if (s == SS - 1) { e0 = 1.0f; e1 = 1.0f; }
        else {
          float js = (float)(s + 1) - 25.5f;
          e0 = fmaf(a0, js, 1.0f);
          e1 = fmaf(a1, js, 1.0f);
        }
        const float* base = C + (size_t)row * ED + 2 * lane;
#pragma unroll
        for (int k = 0; k < 3; ++k) {
          float2 cv = *(const float2*)(base + (size_t)k * NV * ED);
          acc[gg][k].x = fmaf(e0, cv.x, acc[gg][k].x);
          acc[gg][k].y = fmaf(e1, cv.y, acc[gg][k].y);
        }
        f16x2 cv3 = *(const f16x2*)(C3h + (size_t)row * ED + 2 * lane);
        acc[gg][3].x = fmaf(e0, (float)cv3[0], acc[gg][3].x);
        acc[gg][3].y = fmaf(e1, (float)cv3[1], acc[gg][3].y);
        if (!more) break;
        s = s2;
        row = row2;
      }
    }
    __syncthreads();
  }

#pragma unroll
  for (int gg = 0; gg < 4; ++gg) {
    const int bm = bm0 + wave + 4 * gg;
#pragma unroll
    for (int k = 0; k < 4; ++k)
      *(float2*)(Mt + (size_t)k * BMD + (size_t)bm * ED + 2 * lane) = acc[gg][k];
  }
}

// ---------------------------------------------------------------------------
// Kernel B: hop loop — r10-passing version, byte-identical (frozen control).
// ---------------------------------------------------------------------------
__global__ __launch_bounds__(512, 1) void hops_k(
    const int* __restrict__ query, const float* __restrict__ C,
    const float* __restrict__ Tw, const float* __restrict__ Tb,
    const float* __restrict__ Mt, float* __restrict__ U) {
  const int b = blockIdx.x;
  const int tid = threadIdx.x;                   // 0..511
  const int d = tid & 127;
  const int p = tid >> 7;                        // 0..3
  const int wave = tid >> 6, lane = tid & 63;
  __shared__ float tile[NM * ED];                // 102,400 B
  __shared__ float u[ED];
  __shared__ float part[512];
  __shared__ float part2[512];
  __shared__ float sc[NM];
  __shared__ float sc2[NM];

  {
    const float4* s4 = (const float4*)(Mt + (size_t)b * NM * ED);
    float4* t4 = (float4*)tile;
    float4 st[13];
#pragma unroll
    for (int j = 0; j < 13; ++j) {
      int i = tid + 512 * j;
      st[j] = (i < NM * ED / 4) ? s4[i] : make_float4(0.f, 0.f, 0.f, 0.f);
    }
#pragma unroll
    for (int j = 0; j < 13; ++j) {
      int i = tid + 512 * j;
      if (i < NM * ED / 4) t4[i] = st[j];
    }
  }

  {
    const float ad = ((float)(d + 1) - 64.5f) * 6.25e-4f;
    int rows[13];
#pragma unroll
    for (int j = 0; j < 13; ++j) {
      int s = p + 4 * j;
      rows[j] = query[b * SS + (s < SS ? s : 0)];
    }
    float cv[13];
#pragma unroll
    for (int j = 0; j < 13; ++j)
      cv[j] = C[(size_t)rows[j] * ED + d];
    float accv = 0.f;
#pragma unroll
    for (int j = 0; j < 13; ++j) {
      int s = p + 4 * j;
      float e;
      if (s >= SS) e = 0.f;
      else if (s == SS - 1) e = 1.0f;
      else e = fmaf(ad, (float)(s + 1) - 25.5f, 1.0f);
      accv = fmaf(e, cv[j], accv);
    }
    part[tid] = accv;
  }
  __syncthreads();
  if (tid < ED)
    u[tid] = part[tid] + part[tid + 128] + part[tid + 256] + part[tid + 384];
  __syncthreads();

  for (int hop = 0; hop < 3; ++hop) {
    const float* Tn = Mt + (size_t)(hop + 1) * BMD + (size_t)b * NM * ED;
    float pf[50];
#pragma unroll
    for (int j = 0; j < 50; ++j)
      pf[j] = Tn[(size_t)(p + 4 * j) * ED + d];

    {
      float u0v = u[2 * lane], u1v = u[2 * lane + 1];
      for (int m = wave; m < NM; m += 16) {
        const int m2 = m + 8;
        const bool has2 = (m2 < NM);
        float2 r0 = *(const float2*)&tile[m * ED + 2 * lane];
        float pa = r0.x * u0v + r0.y * u1v;
        float pb = 0.f;
        if (has2) {
          float2 r1 = *(const float2*)&tile[m2 * ED + 2 * lane];
          pb = r1.x * u0v + r1.y * u1v;
        }
#pragma unroll
        for (int off = 32; off; off >>= 1) {
          pa += __shfl_xor(pa, off);
          pb += __shfl_xor(pb, off);
        }
        if (lane == 0) {
          sc[m] = pa;
          if (has2) sc[m2] = pb;
        }
      }
    }
    __syncthreads();                               // B1: raw scores ready

    const bool has3 = (lane + 192 < NM);           // lane < 8
    float v0 = sc[lane];
    float v1 = sc[lane + 64];
    float v2 = sc[lane + 128];
    float v3 = has3 ? sc[lane + 192] : -1e30f;
    float mx = fmaxf(fmaxf(v0, v1), fmaxf(v2, v3));
#pragma unroll
    for (int off = 32; off; off >>= 1) mx = fmaxf(mx, __shfl_xor(mx, off));
    float e0 = __expf(v0 - mx), e1 = __expf(v1 - mx), e2 = __expf(v2 - mx);
    float e3 = has3 ? __expf(v3 - mx) : 0.f;
    float ts = e0 + e1 + e2 + e3;
#pragma unroll
    for (int off = 32; off; off >>= 1) ts += __shfl_xor(ts, off);
    const float inv = 1.0f / ts;
    if (wave == 0) {
      sc2[lane] = e0; sc2[lane + 64] = e1; sc2[lane + 128] = e2;
      if (has3) sc2[lane + 192] = e3;
    }
    __syncthreads();                               // B2: sc2 = exp values

    {
      float oacc = 0.f;
#pragma unroll
      for (int j = 0; j < 50; ++j)
        oacc = fmaf(sc2[p + 4 * j], pf[j], oacc);
      part[tid] = oacc;

      const float4* twr = (const float4*)(Tw + (size_t)d * ED + p * 32);
      float4 tw4[8];
#pragma unroll
      for (int j = 0; j < 8; ++j) tw4[j] = twr[j];
      float tacc = 0.f;
#pragma unroll
      for (int j = 0; j < 8; ++j) {
        tacc = fmaf(u[p * 32 + 4 * j + 0], tw4[j].x, tacc);
        tacc = fmaf(u[p * 32 + 4 * j + 1], tw4[j].y, tacc);
        tacc = fmaf(u[p * 32 + 4 * j + 2], tw4[j].z, tacc);
        tacc = fmaf(u[p * 32 + 4 * j + 3], tw4[j].w, tacc);
      }
      part2[tid] = tacc;

      if (hop < 2) {
#pragma unroll
        for (int j = 0; j < 50; ++j)
          tile[(p + 4 * j) * ED + d] = pf[j];
      }
    }
    __syncthreads();                               // B3: partials ready

    if (tid < ED) {
      float ov = (part[tid] + part[tid + 128] + part[tid + 256]
                  + part[tid + 384]) * inv;
      float dot = part2[tid] + part2[tid + 128] + part2[tid + 256]
                  + part2[tid + 384] + Tb[tid];
      float tk = 1.0f / (1.0f + __expf(-dot));
      u[tid] = (1.0f - tk) * u[tid] + ov * tk;
    }
    __syncthreads();                               // B4: u ready for next hop
  }
  if (tid < ED) U[(size_t)b * ED + tid] = u[tid];
}

// ---------------------------------------------------------------------------
// Kernel C: a_hat = U @ C3^T via f16 MFMA (512 thr, 128 v/block — frozen).
// ---------------------------------------------------------------------------
__global__ __launch_bounds__(512) void out_mm_mfma_k(
    const float* __restrict__ U, const _Float16* __restrict__ C3h,
    float* __restrict__ out) {
  __shared__ _Float16 Ub[ED * 136];   // 34,816 B
  const int tid = threadIdx.x;

  {
    const float4* u4 = (const float4*)U;
#pragma unroll
    for (int j = 0; j < 8; ++j) {
      int i = tid + 512 * j;          // float4 index
      float4 f = u4[i];
      int row = i >> 5;
      int col = (i & 31) * 4;
      f16x4 h;
      h[0] = (_Float16)f.x; h[1] = (_Float16)f.y;
      h[2] = (_Float16)f.z; h[3] = (_Float16)f.w;
      *(f16x4*)&Ub[row * 136 + col] = h;
    }
  }
  __syncthreads();

  const int wave = tid >> 6, lane = tid & 63;
  const int n = lane & 15, q = lane >> 4;
  const int v = blockIdx.x * 128 + wave * 16 + n;
  const bool vok = (v < NV);

  f32x4 acc[8];
#pragma unroll
  for (int mt = 0; mt < 8; ++mt) acc[mt] = (f32x4){0.f, 0.f, 0.f, 0.f};

#pragma unroll
  for (int kt = 0; kt < 4; ++kt) {
    f16x8 bfrag = {};
    if (vok) bfrag = *(const f16x8*)(C3h + (size_t)v * ED + kt * 32 + q * 8);
#pragma unroll
    for (int mt = 0; mt < 8; ++mt) {
      f16x8 afrag = *(const f16x8*)&Ub[(mt * 16 + n) * 136 + kt * 32 + q * 8];
      acc[mt] = __builtin_amdgcn_mfma_f32_16x16x32_f16(afrag, bfrag, acc[mt],
                                                       0, 0, 0);
    }
  }

  if (vok) {
#pragma unroll
    for (int mt = 0; mt < 8; ++mt)
#pragma unroll
      for (int i = 0; i < 4; ++i)
        out[(size_t)(mt * 16 + q * 4 + i) * NV + v] = acc[mt][i];
  }
}

// ---------------------------------------------------------------------------
extern "C" void kernel_launch(void* const* d_in, const int* in_sizes, int n_in,
                              void* d_out, int out_size, void* d_ws, size_t ws_size,
                              hipStream_t stream) {
  const int*   story = (const int*)d_in[0];   // [128,200,50]
  const int*   query = (const int*)d_in[1];   // [128,50]
  const float* C     = (const float*)d_in[2]; // [4,50000,128]
  const float* Tw    = (const float*)d_in[3]; // [128,128]
  const float* Tb    = (const float*)d_in[4]; // [128]
  float* out = (float*)d_out;                 // [128,50000]

  float* wsf = (float*)d_ws;
  float*     Mt  = wsf;                                   // 4*BMD floats
  float*     U   = wsf + (size_t)4 * BMD;                 // 16384 floats
  _Float16*  C3h = (_Float16*)(wsf + (size_t)4 * BMD + NB * ED);

  hipLaunchKernelGGL(cvt_c3_k, dim3(NV * ED / 8 / 256), dim3(256), 0, stream,
                     C + (size_t)3 * NV * ED, C3h);
  hipLaunchKernelGGL(story_embed_k, dim3(NB * NM / 16), dim3(256), 0, stream,
                     story, C, C3h, Mt);
  hipLaunchKernelGGL(hops_k, dim3(NB), dim3(512), 0, stream,
                     query, C, Tw, Tb, Mt, U);
  hipLaunchKernelGGL(out_mm_mfma_k, dim3((NV + 127) / 128), dim3(512), 0, stream,
                     U, C3h, out);
}